// Round 1
// baseline (6776.427 us; speedup 1.0000x reference)
//
#include <hip/hip_runtime.h>
#include <hip/hip_bf16.h>

#define B_ 16
#define N_ 1024
#define C_ 256
#define R_ 8
#define E_ 262144
#define NS_ 32
#define BN_ (B_*N_)
#define BNC_ (BN_*C_)

// ---------------- generic fp32 tiled GEMM ----------------
// C[M,Nc] = act( (accum ? C : 0) + rowscale(A)[M,K] @ Bm[K,Nc] + bias )
// rowscale: if non-null, A row m scaled by 1/max(rowscale[m*rsStride],1)
// act: 0 none, 1 relu, 2 sigmoid
__global__ __launch_bounds__(256) void gemm_k(
    const float* __restrict__ A, const float* __restrict__ Bm,
    const float* __restrict__ bias, const float* __restrict__ rowscale, int rsStride,
    float* __restrict__ C, int M, int K, int Nc, int accum, int act)
{
    __shared__ float As[16][65];
    __shared__ float Bs[16][65];
    const int bm = blockIdx.y * 64, bn = blockIdx.x * 64;
    const int tid = threadIdx.x;
    const int tx = tid & 15, ty = tid >> 4;
    float acc[4][4] = {};
    for (int k0 = 0; k0 < K; k0 += 16) {
        #pragma unroll
        for (int i = 0; i < 4; ++i) {
            int l = tid + 256 * i;           // 0..1023 = 64 rows x 16 k
            int m = l >> 4, kk = l & 15;
            float a = A[(size_t)(bm + m) * K + k0 + kk];
            if (rowscale) a *= 1.0f / fmaxf(rowscale[(size_t)(bm + m) * rsStride], 1.0f);
            As[kk][m] = a;
        }
        #pragma unroll
        for (int i = 0; i < 4; ++i) {
            int l = tid + 256 * i;           // 16 k-rows x 64 n
            int kk = l >> 6, n = l & 63;
            Bs[kk][n] = Bm[(size_t)(k0 + kk) * Nc + bn + n];
        }
        __syncthreads();
        #pragma unroll
        for (int kk = 0; kk < 16; ++kk) {
            float av[4], bv[4];
            #pragma unroll
            for (int i = 0; i < 4; ++i) av[i] = As[kk][ty * 4 + i];
            #pragma unroll
            for (int j = 0; j < 4; ++j) bv[j] = Bs[kk][tx * 4 + j];
            #pragma unroll
            for (int i = 0; i < 4; ++i)
                #pragma unroll
                for (int j = 0; j < 4; ++j)
                    acc[i][j] += av[i] * bv[j];
        }
        __syncthreads();
    }
    #pragma unroll
    for (int i = 0; i < 4; ++i) {
        int m = bm + ty * 4 + i;
        #pragma unroll
        for (int j = 0; j < 4; ++j) {
            int n = bn + tx * 4 + j;
            float val = acc[i][j];
            if (bias) val += bias[n];
            if (accum) val += C[(size_t)m * Nc + n];
            if (act == 1) val = fmaxf(val, 0.0f);
            else if (act == 2) val = 1.0f / (1.0f + __expf(-val));
            C[(size_t)m * Nc + n] = val;
        }
    }
}

// ---------------- attention: one block per (b,n) row ----------------
__global__ __launch_bounds__(256) void attn_k(
    const float* __restrict__ q, const float* __restrict__ k,
    const float* __restrict__ v, float* __restrict__ out)
{
    const int row = blockIdx.x;          // b*N + n
    const int b = row >> 10;
    const int tid = threadIdx.x;
    __shared__ float qs[256];
    __shared__ float ps[1024];
    __shared__ float red[256];
    qs[tid] = q[(size_t)row * 256 + tid];
    __syncthreads();
    const float* kb = k + (size_t)b * 1024 * 256;
    const float4* q4 = (const float4*)qs;
    #pragma unroll
    for (int mi = 0; mi < 4; ++mi) {
        int m = tid + mi * 256;
        const float4* k4 = (const float4*)(kb + (size_t)m * 256);
        float acc = 0.0f;
        for (int c4 = 0; c4 < 64; ++c4) {
            float4 kv = k4[c4], qv = q4[c4];
            acc += kv.x * qv.x + kv.y * qv.y + kv.z * qv.z + kv.w * qv.w;
        }
        ps[m] = acc * 0.0625f;           // 1/sqrt(256)
    }
    __syncthreads();
    float lm = -INFINITY;
    for (int i = tid; i < 1024; i += 256) lm = fmaxf(lm, ps[i]);
    red[tid] = lm; __syncthreads();
    for (int s = 128; s > 0; s >>= 1) { if (tid < s) red[tid] = fmaxf(red[tid], red[tid + s]); __syncthreads(); }
    const float mx = red[0];
    __syncthreads();
    float lsum = 0.0f;
    for (int i = tid; i < 1024; i += 256) { float e = __expf(ps[i] - mx); ps[i] = e; lsum += e; }
    red[tid] = lsum; __syncthreads();
    for (int s = 128; s > 0; s >>= 1) { if (tid < s) red[tid] += red[tid + s]; __syncthreads(); }
    const float inv = 1.0f / red[0];
    __syncthreads();
    const float* vb = v + (size_t)b * 1024 * 256;
    float acc = 0.0f;
    for (int m = 0; m < 1024; ++m) acc += ps[m] * vb[(size_t)m * 256 + tid];
    out[(size_t)row * 256 + tid] = acc * inv;
}

// ---------------- LayerNorm (C=256, one block per row) ----------------
__global__ __launch_bounds__(256) void ln_k(
    const float* __restrict__ in, float* __restrict__ out,
    const float* __restrict__ g, const float* __restrict__ bta, int relu)
{
    const int row = blockIdx.x, tid = threadIdx.x;
    __shared__ float red[256];
    float xv = in[(size_t)row * 256 + tid];
    red[tid] = xv; __syncthreads();
    for (int s = 128; s > 0; s >>= 1) { if (tid < s) red[tid] += red[tid + s]; __syncthreads(); }
    const float mean = red[0] * (1.0f / 256.0f);
    __syncthreads();
    const float d = xv - mean;
    red[tid] = d * d; __syncthreads();
    for (int s = 128; s > 0; s >>= 1) { if (tid < s) red[tid] += red[tid + s]; __syncthreads(); }
    const float var = red[0] * (1.0f / 256.0f);
    float y = d * rsqrtf(var + 1e-5f) * g[tid] + bta[tid];
    if (relu) y = fmaxf(y, 0.0f);
    out[(size_t)row * 256 + tid] = y;
}

// ---------------- gated blend + LayerNorm ----------------
__global__ __launch_bounds__(256) void blend_ln_k(
    const float* __restrict__ gate, const float* __restrict__ aout,
    const float* __restrict__ x, float* __restrict__ out,
    const float* __restrict__ g, const float* __restrict__ bta)
{
    const int row = blockIdx.x, tid = threadIdx.x;
    __shared__ float red[256];
    const size_t i = (size_t)row * 256 + tid;
    const float gt = gate[i];
    float xv = gt * aout[i] + (1.0f - gt) * x[i];
    red[tid] = xv; __syncthreads();
    for (int s = 128; s > 0; s >>= 1) { if (tid < s) red[tid] += red[tid + s]; __syncthreads(); }
    const float mean = red[0] * (1.0f / 256.0f);
    __syncthreads();
    const float d = xv - mean;
    red[tid] = d * d; __syncthreads();
    for (int s = 128; s > 0; s >>= 1) { if (tid < s) red[tid] += red[tid + s]; __syncthreads(); }
    const float var = red[0] * (1.0f / 256.0f);
    out[i] = d * rsqrtf(var + 1e-5f) * g[tid] + bta[tid];
}

// ---------------- confidence second layer: dot(t1_row[128], Wc2) ----------------
__global__ __launch_bounds__(256) void conf_k(
    const float* __restrict__ t1, const float* __restrict__ Wc2,
    const float* __restrict__ bc2, float* __restrict__ conf)
{
    const int w = (blockIdx.x * 256 + threadIdx.x) >> 6;
    const int lane = threadIdx.x & 63;
    if (w >= BN_) return;
    float a = t1[(size_t)w * 128 + lane] * Wc2[lane]
            + t1[(size_t)w * 128 + 64 + lane] * Wc2[64 + lane];
    for (int s = 32; s > 0; s >>= 1) a += __shfl_down(a, s);
    if (lane == 0) conf[w] = 1.0f / (1.0f + __expf(-(a + bc2[0])));
}

__global__ __launch_bounds__(256) void weighted_k(
    const float* __restrict__ val, const float* __restrict__ conf, float* __restrict__ w)
{
    const int i = blockIdx.x * 256 + threadIdx.x;
    w[i] = val[i] * conf[i >> 8];
}

// ---------------- edge (dst, rel) counts ----------------
__global__ __launch_bounds__(256) void count_k(
    const int* __restrict__ dst, const int* __restrict__ et, float* __restrict__ cnt)
{
    const int e = blockIdx.x * 256 + threadIdx.x;
    if (e < E_) atomicAdd(&cnt[(size_t)dst[e] * R_ + et[e]], 1.0f);
}

// ---------------- per-relation segment-sum scatter: S[dst] += xn[src] ----------------
__global__ __launch_bounds__(256) void scatter_k(
    const int* __restrict__ src, const int* __restrict__ dst, const int* __restrict__ et,
    const float* __restrict__ xn, float* __restrict__ S, int rel)
{
    const int wid = (blockIdx.x * blockDim.x + threadIdx.x) >> 6;
    const int lane = threadIdx.x & 63;
    const int nw = (gridDim.x * blockDim.x) >> 6;
    for (int e = wid; e < E_; e += nw) {
        if (et[e] != rel) continue;
        const int s = src[e], d = dst[e];
        float4 val = ((const float4*)(xn + (size_t)s * 256))[lane];
        float* o = S + (size_t)d * 256 + lane * 4;
        atomicAdd(o + 0, val.x); atomicAdd(o + 1, val.y);
        atomicAdd(o + 2, val.z); atomicAdd(o + 3, val.w);
    }
}

// ---------------- conf-weighted pool + super-class head ----------------
__global__ __launch_bounds__(256) void pool_head_k(
    const float* __restrict__ xr, const float* __restrict__ conf,
    const float* __restrict__ Wh, const float* __restrict__ bh, float* __restrict__ out)
{
    const int b = blockIdx.x, tid = threadIdx.x;
    __shared__ float confs[1024];
    __shared__ float red[256];
    __shared__ float pooled[256];
    for (int i = tid; i < 1024; i += 256) confs[i] = conf[b * 1024 + i];
    __syncthreads();
    float s = confs[tid] + confs[tid + 256] + confs[tid + 512] + confs[tid + 768];
    red[tid] = s; __syncthreads();
    for (int st = 128; st > 0; st >>= 1) { if (tid < st) red[tid] += red[tid + st]; __syncthreads(); }
    const float denom = fmaxf(red[0], 1e-8f);
    const float* xb = xr + (size_t)b * 1024 * 256;
    float acc = 0.0f;
    for (int n = 0; n < 1024; ++n) acc += confs[n] * xb[(size_t)n * 256 + tid];
    pooled[tid] = acc / denom;
    __syncthreads();
    if (tid < NS_) {
        float o = bh[tid];
        for (int c = 0; c < 256; ++c) o += pooled[c] * Wh[c * NS_ + tid];
        out[b * NS_ + tid] = o;
    }
}

extern "C" void kernel_launch(void* const* d_in, const int* in_sizes, int n_in,
                              void* d_out, int out_size, void* d_ws, size_t ws_size,
                              hipStream_t stream) {
    const float* x    = (const float*)d_in[0];
    const int*   ei   = (const int*)d_in[1];
    const int*   et   = (const int*)d_in[2];
    const float* Wq   = (const float*)d_in[3];  const float* bq  = (const float*)d_in[4];
    const float* Wk   = (const float*)d_in[5];  const float* bk  = (const float*)d_in[6];
    const float* Wv   = (const float*)d_in[7];  const float* bv  = (const float*)d_in[8];
    const float* Wg   = (const float*)d_in[9];  const float* bg  = (const float*)d_in[10];
    const float* lag  = (const float*)d_in[11]; const float* lab = (const float*)d_in[12];
    const float* Wc1  = (const float*)d_in[13]; const float* bc1 = (const float*)d_in[14];
    const float* Wc2  = (const float*)d_in[15]; const float* bc2 = (const float*)d_in[16];
    const float* Wm   = (const float*)d_in[17]; const float* bm  = (const float*)d_in[18];
    const float* l1g  = (const float*)d_in[19]; const float* l1b = (const float*)d_in[20];
    const float* Wrel = (const float*)d_in[21]; const float* Wroot = (const float*)d_in[22];
    const float* brg  = (const float*)d_in[23];
    const float* l2g  = (const float*)d_in[24]; const float* l2b = (const float*)d_in[25];
    const float* Wh   = (const float*)d_in[26]; const float* bh  = (const float*)d_in[27];
    const int* esrc = ei;
    const int* edst = ei + E_;

    float* ws = (float*)d_ws;
    float* q      = ws;                  // BNC
    float* k      = ws + 4194304;        // BNC
    float* v      = ws + 8388608;        // BNC
    float* aout   = ws + 12582912;       // BNC
    float* gate   = ws + 16777216;       // BNC
    float* valid  = ws + 20971520;       // BNC
    float* t1     = ws + 25165824;       // BN*128
    float* conf   = ws + 27262976;       // BN
    float* wght   = ws + 27279360;       // BNC
    float* xm     = ws + 31473664;       // BNC
    float* xn     = ws + 35667968;       // BNC
    float* S      = ws + 39862272;       // BNC
    float* cnt    = ws + 44056576;       // BN*R
    float* agg    = ws + 44187648;       // BNC
    float* xr     = ws + 48381952;       // BNC
    float* outp   = (float*)d_out;

    dim3 blk(256);
    dim3 gFull(C_ / 64, BN_ / 64);       // (4, 256) for Nc=256
    dim3 gHalf(128 / 64, BN_ / 64);      // (2, 256) for Nc=128

    // --- QKV projections ---
    gemm_k<<<gFull, blk, 0, stream>>>(x, Wq, bq, nullptr, 0, q, BN_, C_, C_, 0, 0);
    gemm_k<<<gFull, blk, 0, stream>>>(x, Wk, bk, nullptr, 0, k, BN_, C_, C_, 0, 0);
    gemm_k<<<gFull, blk, 0, stream>>>(x, Wv, bv, nullptr, 0, v, BN_, C_, C_, 0, 0);
    // --- attention ---
    attn_k<<<BN_, blk, 0, stream>>>(q, k, v, aout);
    // --- gate = sigmoid(out@Wg0 + x@Wg1 + bg) ---
    gemm_k<<<gFull, blk, 0, stream>>>(aout, Wg, bg, nullptr, 0, gate, BN_, C_, C_, 0, 0);
    gemm_k<<<gFull, blk, 0, stream>>>(x, Wg + C_ * C_, nullptr, nullptr, 0, gate, BN_, C_, C_, 1, 2);
    // --- validated = LN(gate*out + (1-gate)*x) ---
    blend_ln_k<<<BN_, blk, 0, stream>>>(gate, aout, x, valid, lag, lab);
    // --- confidence ---
    gemm_k<<<gHalf, blk, 0, stream>>>(valid, Wc1, bc1, nullptr, 0, t1, BN_, C_, 128, 0, 1);
    conf_k<<<BN_ / 4, blk, 0, stream>>>(t1, Wc2, bc2, conf);
    // --- weighted, mixer, LN1 ---
    weighted_k<<<BNC_ / 256, blk, 0, stream>>>(valid, conf, wght);
    gemm_k<<<gFull, blk, 0, stream>>>(x, Wm, bm, nullptr, 0, xm, BN_, C_, C_, 0, 0);
    gemm_k<<<gFull, blk, 0, stream>>>(wght, Wm + C_ * C_, nullptr, nullptr, 0, xm, BN_, C_, C_, 1, 1);
    ln_k<<<BN_, blk, 0, stream>>>(xm, xn, l1g, l1b, 0);
    // --- RGCN: counts, then per-relation segment-mean @ W_rel, plus root ---
    hipMemsetAsync(cnt, 0, (size_t)BN_ * R_ * sizeof(float), stream);
    count_k<<<E_ / 256, blk, 0, stream>>>(edst, et, cnt);
    gemm_k<<<gFull, blk, 0, stream>>>(xn, Wroot, brg, nullptr, 0, agg, BN_, C_, C_, 0, 0);
    for (int r = 0; r < R_; ++r) {
        hipMemsetAsync(S, 0, (size_t)BNC_ * sizeof(float), stream);
        scatter_k<<<1024, blk, 0, stream>>>(esrc, edst, et, xn, S, r);
        gemm_k<<<gFull, blk, 0, stream>>>(S, Wrel + (size_t)r * C_ * C_, nullptr, cnt + r, R_,
                                          agg, BN_, C_, C_, 1, 0);
    }
    ln_k<<<BN_, blk, 0, stream>>>(agg, xr, l2g, l2b, 1);
    // --- pool + head ---
    pool_head_k<<<B_, blk, 0, stream>>>(xr, conf, Wh, bh, outp);
}

// Round 2
// 1371.150 us; speedup vs baseline: 4.9421x; 4.9421x over previous
//
#include <hip/hip_runtime.h>
#include <hip/hip_bf16.h>

#define B_ 16
#define N_ 1024
#define C_ 256
#define R_ 8
#define E_ 262144
#define NS_ 32
#define BN_ (B_*N_)
#define BNC_ (BN_*C_)

typedef __hip_bfloat16 bf16;
typedef __attribute__((ext_vector_type(4))) float f32x4;
typedef __attribute__((ext_vector_type(8))) short bf16x8;

__device__ __forceinline__ float b2f(bf16 x) { return __bfloat162float(x); }
__device__ __forceinline__ bf16  f2b(float x) { return __float2bfloat16(x); }

// async global->LDS, 16B per lane. LDS dest must be wave-uniform base (+lane*16 implicit).
__device__ __forceinline__ void gload16(const void* g, void* l) {
    auto gp = (const __attribute__((address_space(1))) void*)(unsigned long long)g;
    auto lp = (__attribute__((address_space(3))) void*)(unsigned)(unsigned long long)l;
    __builtin_amdgcn_global_load_lds(gp, lp, 16, 0, 0);
}

__device__ __forceinline__ void st_out(bf16* p, float v)  { *p = f2b(v); }
__device__ __forceinline__ void st_out(float* p, float v) { *p = v; }
__device__ __forceinline__ float ldf(const float* p) { return *p; }
__device__ __forceinline__ float ldf(const bf16* p)  { return b2f(*p); }

// ---------------- bf16 MFMA GEMM: C = act(A[M,K] @ B^T + bias) ----------------
// A row-major [M,K] (lda), B stored [N,K] row-major (ldb), C [M,N] (ldc).
// 128x128 tile, BK=32, 4 waves (2x2 of 64x64), mfma_f32_16x16x32_bf16.
// grid = (N/128, M/128, batch); strides sA/sB/sC in elements per batch.
template<int ACT, typename OUT_T>
__global__ __launch_bounds__(256) void gemm_bf16(
    const bf16* __restrict__ A, int lda, long long sA,
    const bf16* __restrict__ Bm, int ldb, long long sB,
    OUT_T* __restrict__ Cc, int ldc, long long sC,
    const float* __restrict__ bias, int K)
{
    __shared__ short As[4096];   // 128 rows x 32 k (bf16)
    __shared__ short Bs[4096];   // 128 cols x 32 k
    const int tid = threadIdx.x;
    const int lane = tid & 63, w = tid >> 6;
    const int wr = w >> 1, wc = w & 1;
    const int bm = blockIdx.y * 128, bn = blockIdx.x * 128;
    const bf16* Ab = A + (size_t)blockIdx.z * sA;
    const bf16* Bb = Bm + (size_t)blockIdx.z * sB;
    OUT_T* Cb = Cc + (size_t)blockIdx.z * sC;

    const int rg = lane >> 2;          // row within 16-row staging group
    const int kg = (lane & 3) * 8;     // k elem offset for staging

    f32x4 acc[4][4];
    const f32x4 zz = {0.f, 0.f, 0.f, 0.f};
    #pragma unroll
    for (int i = 0; i < 4; ++i)
        #pragma unroll
        for (int j = 0; j < 4; ++j) acc[i][j] = zz;

    for (int k0 = 0; k0 < K; k0 += 32) {
        __syncthreads();
        #pragma unroll
        for (int t = 0; t < 2; ++t) {
            gload16(Ab + (size_t)(bm + t*64 + w*16 + rg) * lda + k0 + kg, As + t*2048 + w*512);
            gload16(Bb + (size_t)(bn + t*64 + w*16 + rg) * ldb + k0 + kg, Bs + t*2048 + w*512);
        }
        __syncthreads();
        bf16x8 af[4], bf[4];
        #pragma unroll
        for (int i = 0; i < 4; ++i)
            af[i] = *(const bf16x8*)&As[(wr*64 + i*16 + (lane & 15))*32 + (lane >> 4)*8];
        #pragma unroll
        for (int j = 0; j < 4; ++j)
            bf[j] = *(const bf16x8*)&Bs[(wc*64 + j*16 + (lane & 15))*32 + (lane >> 4)*8];
        #pragma unroll
        for (int i = 0; i < 4; ++i)
            #pragma unroll
            for (int j = 0; j < 4; ++j)
                acc[i][j] = __builtin_amdgcn_mfma_f32_16x16x32_bf16(af[i], bf[j], acc[i][j], 0, 0, 0);
    }

    const int er = (lane >> 4) * 4, ec = lane & 15;
    #pragma unroll
    for (int i = 0; i < 4; ++i) {
        #pragma unroll
        for (int j = 0; j < 4; ++j) {
            const int col = bn + wc*64 + j*16 + ec;
            const float bv = bias ? bias[col] : 0.0f;
            #pragma unroll
            for (int p = 0; p < 4; ++p) {
                const int row = bm + wr*64 + i*16 + er + p;
                float val = acc[i][j][p] + bv;
                if (ACT == 1) val = fmaxf(val, 0.0f);
                if (ACT == 2) val = 1.0f / (1.0f + __expf(-val));
                st_out(&Cb[(size_t)row * ldc + col], val);
            }
        }
    }
}

// ---------------- transpose (+convert) : in [K,Nn] -> out bf16 [Nn,K] ----------------
template<typename TIN>
__global__ __launch_bounds__(256) void transpose_k(
    const TIN* __restrict__ in, bf16* __restrict__ out,
    int K, int Nn, long long sIn, long long sOut)
{
    __shared__ float tile[32][33];
    in  += (size_t)blockIdx.z * sIn;
    out += (size_t)blockIdx.z * sOut;
    const int n0 = blockIdx.x * 32, k0 = blockIdx.y * 32;
    const int tx = threadIdx.x & 31, ty = threadIdx.x >> 5;
    #pragma unroll
    for (int i = 0; i < 4; ++i) {
        int r = ty + i*8;
        tile[r][tx] = ldf(&in[(size_t)(k0 + r) * Nn + n0 + tx]);
    }
    __syncthreads();
    #pragma unroll
    for (int i = 0; i < 4; ++i) {
        int r = ty + i*8;
        out[(size_t)(n0 + r) * K + k0 + tx] = f2b(tile[tx][r]);
    }
}

// ---------------- x fp32 -> bf16 (xb, cat1 right half, cat2 left half) ----------------
__global__ __launch_bounds__(256) void cvt_x_k(const float* __restrict__ x,
    bf16* __restrict__ xb, bf16* __restrict__ cat1, bf16* __restrict__ cat2)
{
    const int i = blockIdx.x * 256 + threadIdx.x;
    const bf16 bv = f2b(x[i]);
    const int row = i >> 8, col = i & 255;
    xb[i] = bv;
    cat1[(size_t)row * 512 + 256 + col] = bv;
    cat2[(size_t)row * 512 + col] = bv;
}

// ---------------- row softmax over 1024 bf16 scores, in place, pre-scale 1/16 ----------------
__global__ __launch_bounds__(256) void softmax_k(bf16* __restrict__ s)
{
    const int row = blockIdx.x, tid = threadIdx.x;
    bf16* rp = s + (size_t)row * 1024;
    __shared__ float ps[1024];
    __shared__ float red[256];
    float lm = -INFINITY;
    for (int i = tid; i < 1024; i += 256) {
        float v = b2f(rp[i]) * 0.0625f;
        ps[i] = v; lm = fmaxf(lm, v);
    }
    red[tid] = lm; __syncthreads();
    for (int st = 128; st > 0; st >>= 1) { if (tid < st) red[tid] = fmaxf(red[tid], red[tid + st]); __syncthreads(); }
    const float mx = red[0]; __syncthreads();
    float lsum = 0.0f;
    for (int i = tid; i < 1024; i += 256) { float e = __expf(ps[i] - mx); ps[i] = e; lsum += e; }
    red[tid] = lsum; __syncthreads();
    for (int st = 128; st > 0; st >>= 1) { if (tid < st) red[tid] += red[tid + st]; __syncthreads(); }
    const float inv = 1.0f / red[0]; __syncthreads();
    for (int i = tid; i < 1024; i += 256) rp[i] = f2b(ps[i] * inv);
}

// ---------------- generic LN over C=256, one block per row ----------------
template<typename TIN, int RELU>
__global__ __launch_bounds__(256) void ln_k(
    const TIN* __restrict__ in, bf16* __restrict__ out,
    const float* __restrict__ g, const float* __restrict__ bta)
{
    const int row = blockIdx.x, tid = threadIdx.x;
    __shared__ float red[256];
    const float xv = ldf(&in[(size_t)row * 256 + tid]);
    red[tid] = xv; __syncthreads();
    for (int s = 128; s > 0; s >>= 1) { if (tid < s) red[tid] += red[tid + s]; __syncthreads(); }
    const float mean = red[0] * (1.0f / 256.0f); __syncthreads();
    const float d = xv - mean;
    red[tid] = d * d; __syncthreads();
    for (int s = 128; s > 0; s >>= 1) { if (tid < s) red[tid] += red[tid + s]; __syncthreads(); }
    const float var = red[0] * (1.0f / 256.0f);
    float y = d * rsqrtf(var + 1e-5f) * g[tid] + bta[tid];
    if (RELU) y = fmaxf(y, 0.0f);
    out[(size_t)row * 256 + tid] = f2b(y);
}

// ---------------- gated blend + LN (aout read from cat1 left half, x fp32) ----------------
__global__ __launch_bounds__(256) void blend_ln_k(
    const bf16* __restrict__ gate, const bf16* __restrict__ cat1,
    const float* __restrict__ x, bf16* __restrict__ valid,
    const float* __restrict__ g, const float* __restrict__ bta)
{
    const int row = blockIdx.x, tid = threadIdx.x;
    __shared__ float red[256];
    const float gt = b2f(gate[(size_t)row * 256 + tid]);
    const float ao = b2f(cat1[(size_t)row * 512 + tid]);
    const float xv = gt * ao + (1.0f - gt) * x[(size_t)row * 256 + tid];
    red[tid] = xv; __syncthreads();
    for (int s = 128; s > 0; s >>= 1) { if (tid < s) red[tid] += red[tid + s]; __syncthreads(); }
    const float mean = red[0] * (1.0f / 256.0f); __syncthreads();
    const float d = xv - mean;
    red[tid] = d * d; __syncthreads();
    for (int s = 128; s > 0; s >>= 1) { if (tid < s) red[tid] += red[tid + s]; __syncthreads(); }
    const float var = red[0] * (1.0f / 256.0f);
    valid[(size_t)row * 256 + tid] = f2b(d * rsqrtf(var + 1e-5f) * g[tid] + bta[tid]);
}

// ---------------- confidence layer 2: sigmoid(dot(t1_row[128], Wc2) + bc2) ----------------
__global__ __launch_bounds__(256) void conf_k(
    const bf16* __restrict__ t1, const float* __restrict__ Wc2,
    const float* __restrict__ bc2, float* __restrict__ conf)
{
    const int gid = blockIdx.x * 256 + threadIdx.x;
    const int wnode = gid >> 6, lane = threadIdx.x & 63;
    if (wnode >= BN_) return;
    float a = b2f(t1[(size_t)wnode * 128 + lane]) * Wc2[lane]
            + b2f(t1[(size_t)wnode * 128 + 64 + lane]) * Wc2[64 + lane];
    for (int s = 32; s > 0; s >>= 1) a += __shfl_down(a, s);
    if (lane == 0) conf[wnode] = 1.0f / (1.0f + __expf(-(a + bc2[0])));
}

// ---------------- weighted = valid * conf  -> cat2 right half ----------------
__global__ __launch_bounds__(256) void weighted_k(
    const bf16* __restrict__ valid, const float* __restrict__ conf, bf16* __restrict__ cat2)
{
    const int i = blockIdx.x * 256 + threadIdx.x;
    const int row = i >> 8, col = i & 255;
    cat2[(size_t)row * 512 + 256 + col] = f2b(b2f(valid[i]) * conf[row]);
}

// ---------------- per-(dst,rel) edge counts ----------------
__global__ __launch_bounds__(256) void count_k(
    const int* __restrict__ dst, const int* __restrict__ et, float* __restrict__ cnt)
{
    const int e = blockIdx.x * 256 + threadIdx.x;
    if (e < E_) atomicAdd(&cnt[(size_t)dst[e] * R_ + et[e]], 1.0f);
}

// ---------------- scatter: agg[dst] += h[src] / cnt[dst,rel] for edges of `rel` ----------------
__global__ __launch_bounds__(256) void scatter_k(
    const int* __restrict__ src, const int* __restrict__ dst, const int* __restrict__ et,
    const bf16* __restrict__ h, const float* __restrict__ cnt,
    float* __restrict__ agg, int rel)
{
    const int wid = (blockIdx.x * blockDim.x + threadIdx.x) >> 6;
    const int lane = threadIdx.x & 63;
    const int nw = (gridDim.x * blockDim.x) >> 6;
    for (int e = wid; e < E_; e += nw) {
        if (et[e] != rel) continue;
        const int s = src[e], d = dst[e];
        const float inv = 1.0f / fmaxf(cnt[(size_t)d * R_ + rel], 1.0f);
        const unsigned* hp = (const unsigned*)(h + (size_t)s * 256);
        const unsigned u0 = hp[lane * 2], u1 = hp[lane * 2 + 1];
        const float f0 = __uint_as_float(u0 << 16);
        const float f1 = __uint_as_float(u0 & 0xffff0000u);
        const float f2 = __uint_as_float(u1 << 16);
        const float f3 = __uint_as_float(u1 & 0xffff0000u);
        float* o = agg + (size_t)d * 256 + lane * 4;
        atomicAdd(o + 0, f0 * inv); atomicAdd(o + 1, f1 * inv);
        atomicAdd(o + 2, f2 * inv); atomicAdd(o + 3, f3 * inv);
    }
}

// ---------------- pooling stage 1: partial conf-weighted sums over 64-node chunks ----------------
__global__ __launch_bounds__(256) void pool1_k(
    const bf16* __restrict__ xr, const float* __restrict__ conf, float* __restrict__ partial)
{
    const int b = blockIdx.x, chunk = blockIdx.y, c = threadIdx.x;
    float acc = 0.0f;
    for (int n = 0; n < 64; ++n) {
        const int node = b * 1024 + chunk * 64 + n;
        acc += conf[node] * b2f(xr[(size_t)node * 256 + c]);
    }
    partial[(size_t)(b * 16 + chunk) * 256 + c] = acc;
}

// ---------------- pooling stage 2 + head ----------------
__global__ __launch_bounds__(256) void pool2_k(
    const float* __restrict__ partial, const float* __restrict__ conf,
    const float* __restrict__ Wh, const float* __restrict__ bh, float* __restrict__ out)
{
    const int b = blockIdx.x, tid = threadIdx.x;
    __shared__ float red[256];
    __shared__ float pooled[256];
    float pc = 0.0f;
    for (int ch = 0; ch < 16; ++ch) pc += partial[(size_t)(b * 16 + ch) * 256 + tid];
    float s = conf[b * 1024 + tid] + conf[b * 1024 + 256 + tid]
            + conf[b * 1024 + 512 + tid] + conf[b * 1024 + 768 + tid];
    red[tid] = s; __syncthreads();
    for (int st = 128; st > 0; st >>= 1) { if (tid < st) red[tid] += red[tid + st]; __syncthreads(); }
    const float denom = fmaxf(red[0], 1e-8f);
    pooled[tid] = pc / denom;
    __syncthreads();
    if (tid < NS_) {
        float o = bh[tid];
        for (int c = 0; c < 256; ++c) o += pooled[c] * Wh[c * NS_ + tid];
        out[b * NS_ + tid] = o;
    }
}

extern "C" void kernel_launch(void* const* d_in, const int* in_sizes, int n_in,
                              void* d_out, int out_size, void* d_ws, size_t ws_size,
                              hipStream_t stream) {
    const float* x    = (const float*)d_in[0];
    const int*   ei   = (const int*)d_in[1];
    const int*   et   = (const int*)d_in[2];
    const float* Wq   = (const float*)d_in[3];  const float* bq  = (const float*)d_in[4];
    const float* Wk   = (const float*)d_in[5];  const float* bk  = (const float*)d_in[6];
    const float* Wv   = (const float*)d_in[7];  const float* bv  = (const float*)d_in[8];
    const float* Wg   = (const float*)d_in[9];  const float* bg  = (const float*)d_in[10];
    const float* lag  = (const float*)d_in[11]; const float* lab = (const float*)d_in[12];
    const float* Wc1  = (const float*)d_in[13]; const float* bc1 = (const float*)d_in[14];
    const float* Wc2  = (const float*)d_in[15]; const float* bc2 = (const float*)d_in[16];
    const float* Wm   = (const float*)d_in[17]; const float* bm  = (const float*)d_in[18];
    const float* l1g  = (const float*)d_in[19]; const float* l1b = (const float*)d_in[20];
    const float* Wrel = (const float*)d_in[21]; const float* Wroot = (const float*)d_in[22];
    const float* brg  = (const float*)d_in[23];
    const float* l2g  = (const float*)d_in[24]; const float* l2b = (const float*)d_in[25];
    const float* Wh   = (const float*)d_in[26]; const float* bh  = (const float*)d_in[27];
    const int* esrc = ei;
    const int* edst = ei + E_;

    char* w8 = (char*)d_ws;
    bf16*  xb    = (bf16*)(w8 + 0);            // 8 MB
    bf16*  qb    = (bf16*)(w8 + 8388608);      // 8 MB
    bf16*  kb    = (bf16*)(w8 + 16777216);     // 8 MB
    bf16*  vb    = (bf16*)(w8 + 25165824);     // 8 MB
    bf16*  vtb   = (bf16*)(w8 + 33554432);     // 8 MB
    bf16*  sP    = (bf16*)(w8 + 41943040);     // 32 MB  scores -> P in place
    bf16*  cat1  = (bf16*)(w8 + 75497472);     // 16 MB  [aout | xb]
    bf16*  cat2  = (bf16*)(w8 + 92274688);     // 16 MB  [xb | weighted]
    bf16*  gate  = (bf16*)(w8 + 109051904);    // 8 MB
    bf16*  valid = (bf16*)(w8 + 117440512);    // 8 MB
    bf16*  t1    = (bf16*)(w8 + 125829120);    // 4 MB
    bf16*  xm    = (bf16*)(w8 + 130023424);    // 8 MB
    bf16*  xn    = (bf16*)(w8 + 138412032);    // 8 MB
    bf16*  hbuf  = (bf16*)(w8 + 146800640);    // 8 MB
    float* agg   = (float*)(w8 + 155189248);   // 16 MB
    bf16*  xr    = (bf16*)(w8 + 171966464);    // 8 MB
    float* conf  = (float*)(w8 + 180355072);   // 64 KB
    float* cnt   = (float*)(w8 + 180420608);   // 512 KB
    float* part  = (float*)(w8 + 180944896);   // 256 KB
    bf16*  WT    = (bf16*)(w8 + 181207040);    // ~2.2 MB of transposed weights
    bf16* WqT   = WT;
    bf16* WkT   = WT + 65536;
    bf16* WvT   = WT + 131072;
    bf16* WrootT= WT + 196608;
    bf16* WgT   = WT + 262144;     // [256,512]
    bf16* WmT   = WT + 393216;     // [256,512]
    bf16* Wc1T  = WT + 524288;     // [128,256]
    bf16* WrelT = WT + 557056;     // 8 x [256,256]
    float* outp = (float*)d_out;

    dim3 blk(256);

    // --- prep: convert/transpose ---
    cvt_x_k<<<BNC_ / 256, blk, 0, stream>>>(x, xb, cat1, cat2);
    transpose_k<float><<<dim3(8, 8, 1),  blk, 0, stream>>>(Wq,   WqT,    256, 256, 0, 0);
    transpose_k<float><<<dim3(8, 8, 1),  blk, 0, stream>>>(Wk,   WkT,    256, 256, 0, 0);
    transpose_k<float><<<dim3(8, 8, 1),  blk, 0, stream>>>(Wv,   WvT,    256, 256, 0, 0);
    transpose_k<float><<<dim3(8, 8, 1),  blk, 0, stream>>>(Wroot,WrootT, 256, 256, 0, 0);
    transpose_k<float><<<dim3(8, 16, 1), blk, 0, stream>>>(Wg,   WgT,    512, 256, 0, 0);
    transpose_k<float><<<dim3(8, 16, 1), blk, 0, stream>>>(Wm,   WmT,    512, 256, 0, 0);
    transpose_k<float><<<dim3(4, 8, 1),  blk, 0, stream>>>(Wc1,  Wc1T,   256, 128, 0, 0);
    transpose_k<float><<<dim3(8, 8, 8),  blk, 0, stream>>>(Wrel, WrelT,  256, 256, 65536, 65536);

    // --- QKV projections (bf16 MFMA) ---
    gemm_bf16<0, bf16><<<dim3(2, 128, 1), blk, 0, stream>>>(xb, 256, 0, WqT, 256, 0, qb, 256, 0, bq, 256);
    gemm_bf16<0, bf16><<<dim3(2, 128, 1), blk, 0, stream>>>(xb, 256, 0, WkT, 256, 0, kb, 256, 0, bk, 256);
    gemm_bf16<0, bf16><<<dim3(2, 128, 1), blk, 0, stream>>>(xb, 256, 0, WvT, 256, 0, vb, 256, 0, bv, 256);
    // V^T per batch for the PV GEMM B-operand
    transpose_k<bf16><<<dim3(8, 32, 16), blk, 0, stream>>>(vb, vtb, 1024, 256, 262144, 262144);

    // --- attention: scores = Q @ K^T (batched), softmax, O = P @ V ---
    gemm_bf16<0, bf16><<<dim3(8, 8, 16), blk, 0, stream>>>(
        qb, 256, 262144, kb, 256, 262144, sP, 1024, 1048576, nullptr, 256);
    softmax_k<<<BN_, blk, 0, stream>>>(sP);
    gemm_bf16<0, bf16><<<dim3(2, 8, 16), blk, 0, stream>>>(
        sP, 1024, 1048576, vtb, 1024, 262144, cat1, 512, 524288, nullptr, 1024);

    // --- gate = sigmoid([aout|x] @ Wg + bg), blended LN ---
    gemm_bf16<2, bf16><<<dim3(2, 128, 1), blk, 0, stream>>>(cat1, 512, 0, WgT, 512, 0, gate, 256, 0, bg, 512);
    blend_ln_k<<<BN_, blk, 0, stream>>>(gate, cat1, x, valid, lag, lab);

    // --- confidence ---
    gemm_bf16<1, bf16><<<dim3(1, 128, 1), blk, 0, stream>>>(valid, 256, 0, Wc1T, 256, 0, t1, 128, 0, bc1, 256);
    conf_k<<<BN_ / 4, blk, 0, stream>>>(t1, Wc2, bc2, conf);
    weighted_k<<<BNC_ / 256, blk, 0, stream>>>(valid, conf, cat2);

    // --- mixer + LN1 ---
    gemm_bf16<1, bf16><<<dim3(2, 128, 1), blk, 0, stream>>>(cat2, 512, 0, WmT, 512, 0, xm, 256, 0, bm, 512);
    ln_k<bf16, 0><<<BN_, blk, 0, stream>>>(xm, xn, l1g, l1b);

    // --- RGCN: counts, root, then per-relation transform + scatter-mean ---
    hipMemsetAsync(cnt, 0, (size_t)BN_ * R_ * sizeof(float), stream);
    count_k<<<E_ / 256, blk, 0, stream>>>(edst, et, cnt);
    gemm_bf16<0, float><<<dim3(2, 128, 1), blk, 0, stream>>>(xn, 256, 0, WrootT, 256, 0, agg, 256, 0, brg, 256);
    for (int r = 0; r < R_; ++r) {
        gemm_bf16<0, bf16><<<dim3(2, 128, 1), blk, 0, stream>>>(
            xn, 256, 0, WrelT + (size_t)r * 65536, 256, 0, hbuf, 256, 0, nullptr, 256);
        scatter_k<<<1024, blk, 0, stream>>>(esrc, edst, et, hbuf, cnt, agg, r);
    }
    ln_k<float, 1><<<BN_, blk, 0, stream>>>(agg, xr, l2g, l2b);

    // --- pool + head ---
    pool1_k<<<dim3(B_, 16), blk, 0, stream>>>(xr, conf, part);
    pool2_k<<<B_, blk, 0, stream>>>(part, conf, Wh, bh, outp);
}

// Round 3
// 396.895 us; speedup vs baseline: 17.0736x; 3.4547x over previous
//
#include <hip/hip_runtime.h>
#include <hip/hip_bf16.h>

#define B_ 16
#define N_ 1024
#define C_ 256
#define R_ 8
#define E_ 262144
#define NS_ 32
#define BN_ (B_*N_)
#define BNC_ (BN_*C_)

typedef __hip_bfloat16 bf16;
typedef __attribute__((ext_vector_type(4))) float f32x4;
typedef __attribute__((ext_vector_type(8))) short bf16x8;

__device__ __forceinline__ float b2f(bf16 x) { return __bfloat162float(x); }
__device__ __forceinline__ bf16  f2b(float x) { return __float2bfloat16(x); }

// async global->LDS, 16B per lane. LDS dest must be wave-uniform base (+lane*16 implicit).
__device__ __forceinline__ void gload16(const void* g, void* l) {
    auto gp = (const __attribute__((address_space(1))) void*)(unsigned long long)g;
    auto lp = (__attribute__((address_space(3))) void*)(unsigned)(unsigned long long)l;
    __builtin_amdgcn_global_load_lds(gp, lp, 16, 0, 0);
}

__device__ __forceinline__ void st_out(bf16* p, float v)  { *p = f2b(v); }
__device__ __forceinline__ void st_out(float* p, float v) { *p = v; }
__device__ __forceinline__ float ldf(const float* p) { return *p; }
__device__ __forceinline__ float ldf(const bf16* p)  { return b2f(*p); }

// ---------------- bf16 MFMA GEMM: C = act(A[M,K] @ B^T + bias) ----------------
// A row-major [M,K] (lda), B stored [N,K] row-major (ldb), C [M,N] (ldc).
// 128x128 tile, BK=32, 4 waves (2x2 of 64x64), mfma_f32_16x16x32_bf16.
template<int ACT, typename OUT_T>
__global__ __launch_bounds__(256) void gemm_bf16(
    const bf16* __restrict__ A, int lda, long long sA,
    const bf16* __restrict__ Bm, int ldb, long long sB,
    OUT_T* __restrict__ Cc, int ldc, long long sC,
    const float* __restrict__ bias, int K)
{
    __shared__ short As[4096];   // 128 rows x 32 k (bf16)
    __shared__ short Bs[4096];   // 128 cols x 32 k
    const int tid = threadIdx.x;
    const int lane = tid & 63, w = tid >> 6;
    const int wr = w >> 1, wc = w & 1;
    const int bm = blockIdx.y * 128, bn = blockIdx.x * 128;
    const bf16* Ab = A + (size_t)blockIdx.z * sA;
    const bf16* Bb = Bm + (size_t)blockIdx.z * sB;
    OUT_T* Cb = Cc + (size_t)blockIdx.z * sC;

    const int rg = lane >> 2;          // row within 16-row staging group
    const int kg = (lane & 3) * 8;     // k elem offset for staging

    f32x4 acc[4][4];
    const f32x4 zz = {0.f, 0.f, 0.f, 0.f};
    #pragma unroll
    for (int i = 0; i < 4; ++i)
        #pragma unroll
        for (int j = 0; j < 4; ++j) acc[i][j] = zz;

    for (int k0 = 0; k0 < K; k0 += 32) {
        __syncthreads();
        #pragma unroll
        for (int t = 0; t < 2; ++t) {
            gload16(Ab + (size_t)(bm + t*64 + w*16 + rg) * lda + k0 + kg, As + t*2048 + w*512);
            gload16(Bb + (size_t)(bn + t*64 + w*16 + rg) * ldb + k0 + kg, Bs + t*2048 + w*512);
        }
        __syncthreads();
        bf16x8 af[4], bf[4];
        #pragma unroll
        for (int i = 0; i < 4; ++i)
            af[i] = *(const bf16x8*)&As[(wr*64 + i*16 + (lane & 15))*32 + (lane >> 4)*8];
        #pragma unroll
        for (int j = 0; j < 4; ++j)
            bf[j] = *(const bf16x8*)&Bs[(wc*64 + j*16 + (lane & 15))*32 + (lane >> 4)*8];
        #pragma unroll
        for (int i = 0; i < 4; ++i)
            #pragma unroll
            for (int j = 0; j < 4; ++j)
                acc[i][j] = __builtin_amdgcn_mfma_f32_16x16x32_bf16(af[i], bf[j], acc[i][j], 0, 0, 0);
    }

    const int er = (lane >> 4) * 4, ec = lane & 15;
    #pragma unroll
    for (int i = 0; i < 4; ++i) {
        #pragma unroll
        for (int j = 0; j < 4; ++j) {
            const int col = bn + wc*64 + j*16 + ec;
            const float bv = bias ? bias[col] : 0.0f;
            #pragma unroll
            for (int p = 0; p < 4; ++p) {
                const int row = bm + wr*64 + i*16 + er + p;
                float val = acc[i][j][p] + bv;
                if (ACT == 1) val = fmaxf(val, 0.0f);
                if (ACT == 2) val = 1.0f / (1.0f + __expf(-val));
                st_out(&Cb[(size_t)row * ldc + col], val);
            }
        }
    }
}

// ---------------- transpose (+convert) : in [K,Nn] -> out bf16 [Nn,K] ----------------
template<typename TIN>
__global__ __launch_bounds__(256) void transpose_k(
    const TIN* __restrict__ in, bf16* __restrict__ out,
    int K, int Nn, long long sIn, long long sOut)
{
    __shared__ float tile[32][33];
    in  += (size_t)blockIdx.z * sIn;
    out += (size_t)blockIdx.z * sOut;
    const int n0 = blockIdx.x * 32, k0 = blockIdx.y * 32;
    const int tx = threadIdx.x & 31, ty = threadIdx.x >> 5;
    #pragma unroll
    for (int i = 0; i < 4; ++i) {
        int r = ty + i*8;
        tile[r][tx] = ldf(&in[(size_t)(k0 + r) * Nn + n0 + tx]);
    }
    __syncthreads();
    #pragma unroll
    for (int i = 0; i < 4; ++i) {
        int r = ty + i*8;
        out[(size_t)(n0 + r) * K + k0 + tx] = f2b(tile[tx][r]);
    }
}

// ---------------- x fp32 -> bf16 (xb, cat1 right half, cat2 left half) ----------------
__global__ __launch_bounds__(256) void cvt_x_k(const float* __restrict__ x,
    bf16* __restrict__ xb, bf16* __restrict__ cat1, bf16* __restrict__ cat2)
{
    const int i = blockIdx.x * 256 + threadIdx.x;
    const bf16 bv = f2b(x[i]);
    const int row = i >> 8, col = i & 255;
    xb[i] = bv;
    cat1[(size_t)row * 512 + 256 + col] = bv;
    cat2[(size_t)row * 512 + col] = bv;
}

// ---------------- row softmax over 1024 bf16 scores, in place, pre-scale 1/16 ----------------
__global__ __launch_bounds__(256) void softmax_k(bf16* __restrict__ s)
{
    const int row = blockIdx.x, tid = threadIdx.x;
    bf16* rp = s + (size_t)row * 1024;
    __shared__ float ps[1024];
    __shared__ float red[256];
    float lm = -INFINITY;
    for (int i = tid; i < 1024; i += 256) {
        float v = b2f(rp[i]) * 0.0625f;
        ps[i] = v; lm = fmaxf(lm, v);
    }
    red[tid] = lm; __syncthreads();
    for (int st = 128; st > 0; st >>= 1) { if (tid < st) red[tid] = fmaxf(red[tid], red[tid + st]); __syncthreads(); }
    const float mx = red[0]; __syncthreads();
    float lsum = 0.0f;
    for (int i = tid; i < 1024; i += 256) { float e = __expf(ps[i] - mx); ps[i] = e; lsum += e; }
    red[tid] = lsum; __syncthreads();
    for (int st = 128; st > 0; st >>= 1) { if (tid < st) red[tid] += red[tid + st]; __syncthreads(); }
    const float inv = 1.0f / red[0]; __syncthreads();
    for (int i = tid; i < 1024; i += 256) rp[i] = f2b(ps[i] * inv);
}

// ---------------- generic LN over C=256, one block per row ----------------
template<typename TIN, int RELU>
__global__ __launch_bounds__(256) void ln_k(
    const TIN* __restrict__ in, bf16* __restrict__ out,
    const float* __restrict__ g, const float* __restrict__ bta)
{
    const int row = blockIdx.x, tid = threadIdx.x;
    __shared__ float red[256];
    const float xv = ldf(&in[(size_t)row * 256 + tid]);
    red[tid] = xv; __syncthreads();
    for (int s = 128; s > 0; s >>= 1) { if (tid < s) red[tid] += red[tid + s]; __syncthreads(); }
    const float mean = red[0] * (1.0f / 256.0f); __syncthreads();
    const float d = xv - mean;
    red[tid] = d * d; __syncthreads();
    for (int s = 128; s > 0; s >>= 1) { if (tid < s) red[tid] += red[tid + s]; __syncthreads(); }
    const float var = red[0] * (1.0f / 256.0f);
    float y = d * rsqrtf(var + 1e-5f) * g[tid] + bta[tid];
    if (RELU) y = fmaxf(y, 0.0f);
    out[(size_t)row * 256 + tid] = f2b(y);
}

// ---------------- gated blend + LN (aout read from cat1 left half, x fp32) ----------------
__global__ __launch_bounds__(256) void blend_ln_k(
    const bf16* __restrict__ gate, const bf16* __restrict__ cat1,
    const float* __restrict__ x, bf16* __restrict__ valid,
    const float* __restrict__ g, const float* __restrict__ bta)
{
    const int row = blockIdx.x, tid = threadIdx.x;
    __shared__ float red[256];
    const float gt = b2f(gate[(size_t)row * 256 + tid]);
    const float ao = b2f(cat1[(size_t)row * 512 + tid]);
    const float xv = gt * ao + (1.0f - gt) * x[(size_t)row * 256 + tid];
    red[tid] = xv; __syncthreads();
    for (int s = 128; s > 0; s >>= 1) { if (tid < s) red[tid] += red[tid + s]; __syncthreads(); }
    const float mean = red[0] * (1.0f / 256.0f); __syncthreads();
    const float d = xv - mean;
    red[tid] = d * d; __syncthreads();
    for (int s = 128; s > 0; s >>= 1) { if (tid < s) red[tid] += red[tid + s]; __syncthreads(); }
    const float var = red[0] * (1.0f / 256.0f);
    valid[(size_t)row * 256 + tid] = f2b(d * rsqrtf(var + 1e-5f) * g[tid] + bta[tid]);
}

// ---------------- confidence layer 2: sigmoid(dot(t1_row[128], Wc2) + bc2) ----------------
__global__ __launch_bounds__(256) void conf_k(
    const bf16* __restrict__ t1, const float* __restrict__ Wc2,
    const float* __restrict__ bc2, float* __restrict__ conf)
{
    const int gid = blockIdx.x * 256 + threadIdx.x;
    const int wnode = gid >> 6, lane = threadIdx.x & 63;
    if (wnode >= BN_) return;
    float a = b2f(t1[(size_t)wnode * 128 + lane]) * Wc2[lane]
            + b2f(t1[(size_t)wnode * 128 + 64 + lane]) * Wc2[64 + lane];
    for (int s = 32; s > 0; s >>= 1) a += __shfl_down(a, s);
    if (lane == 0) conf[wnode] = 1.0f / (1.0f + __expf(-(a + bc2[0])));
}

// ---------------- weighted = valid * conf  -> cat2 right half ----------------
__global__ __launch_bounds__(256) void weighted_k(
    const bf16* __restrict__ valid, const float* __restrict__ conf, bf16* __restrict__ cat2)
{
    const int i = blockIdx.x * 256 + threadIdx.x;
    const int row = i >> 8, col = i & 255;
    cat2[(size_t)row * 512 + 256 + col] = f2b(b2f(valid[i]) * conf[row]);
}

// ---------------- CSR build: degree + per-(dst,rel) counts ----------------
__global__ __launch_bounds__(256) void count2_k(
    const int* __restrict__ dst, const int* __restrict__ et,
    int* __restrict__ deg, int* __restrict__ cnt8)
{
    const int e = blockIdx.x * 256 + threadIdx.x;
    if (e < E_) {
        const int d = dst[e];
        atomicAdd(&deg[d], 1);
        atomicAdd(&cnt8[d * 8 + et[e]], 1);
    }
}

// single block, 256 threads: exclusive prefix scan of deg[16384] -> rowptr, cursor
__global__ __launch_bounds__(256) void scan_k(
    const int* __restrict__ deg, int* __restrict__ rowptr, int* __restrict__ cursor)
{
    __shared__ int part[256];
    const int tid = threadIdx.x;
    const int base = tid * 64;
    int s = 0;
    for (int i = 0; i < 64; ++i) s += deg[base + i];
    part[tid] = s; __syncthreads();
    for (int off = 1; off < 256; off <<= 1) {
        int t = (tid >= off) ? part[tid - off] : 0;
        __syncthreads();
        part[tid] += t;
        __syncthreads();
    }
    int run = (tid == 0) ? 0 : part[tid - 1];
    for (int i = 0; i < 64; ++i) {
        rowptr[base + i] = run;
        cursor[base + i] = run;
        run += deg[base + i];
    }
    if (tid == 255) rowptr[BN_] = run;
}

__global__ __launch_bounds__(256) void fill_k(
    const int* __restrict__ src, const int* __restrict__ dst, const int* __restrict__ et,
    int* __restrict__ cursor, int* __restrict__ elist)
{
    const int e = blockIdx.x * 256 + threadIdx.x;
    if (e < E_) {
        const int pos = atomicAdd(&cursor[dst[e]], 1);
        elist[pos] = src[e] | (et[e] << 16);
    }
}

// ---------------- RGCN gather + root-add + LN2 + relu (one wave per node) ----------------
__global__ __launch_bounds__(256) void gather_ln_k(
    const int* __restrict__ rowptr, const int* __restrict__ elist,
    const bf16* __restrict__ h,      // [BN, 2048] = per-rel transformed nodes
    const int* __restrict__ cnt8,    // [BN, 8]
    const float* __restrict__ rootb, // [BN, 256] fp32 (xn@Wroot + b)
    const float* __restrict__ g, const float* __restrict__ bta,
    bf16* __restrict__ xr)
{
    const int node = blockIdx.x * 4 + (threadIdx.x >> 6);
    const int lane = threadIdx.x & 63;
    const int e0 = rowptr[node], e1 = rowptr[node + 1];
    float invc[8];
    #pragma unroll
    for (int r = 0; r < 8; ++r)
        invc[r] = 1.0f / fmaxf((float)cnt8[node * 8 + r], 1.0f);
    float a0 = 0.f, a1 = 0.f, a2 = 0.f, a3 = 0.f;
    for (int e = e0; e < e1; ++e) {
        const int pe = elist[e];
        const int srcn = pe & 0xffff, rel = pe >> 16;
        const float w = invc[rel];
        const ushort4 hv = *(const ushort4*)(h + (size_t)srcn * 2048 + rel * 256 + lane * 4);
        a0 += w * __uint_as_float((unsigned)hv.x << 16);
        a1 += w * __uint_as_float((unsigned)hv.y << 16);
        a2 += w * __uint_as_float((unsigned)hv.z << 16);
        a3 += w * __uint_as_float((unsigned)hv.w << 16);
    }
    const float4 rt = *(const float4*)(rootb + (size_t)node * 256 + lane * 4);
    const float v0 = a0 + rt.x, v1 = a1 + rt.y, v2 = a2 + rt.z, v3 = a3 + rt.w;
    float s  = v0 + v1 + v2 + v3;
    float sq = v0*v0 + v1*v1 + v2*v2 + v3*v3;
    #pragma unroll
    for (int m = 32; m >= 1; m >>= 1) { s += __shfl_xor(s, m); sq += __shfl_xor(sq, m); }
    const float mean = s * (1.0f / 256.0f);
    const float var  = sq * (1.0f / 256.0f) - mean * mean;
    const float rs = rsqrtf(var + 1e-5f);
    const float4 gv = *(const float4*)(g + lane * 4);
    const float4 bv = *(const float4*)(bta + lane * 4);
    bf16 tb[4];
    tb[0] = f2b(fmaxf((v0 - mean) * rs * gv.x + bv.x, 0.f));
    tb[1] = f2b(fmaxf((v1 - mean) * rs * gv.y + bv.y, 0.f));
    tb[2] = f2b(fmaxf((v2 - mean) * rs * gv.z + bv.z, 0.f));
    tb[3] = f2b(fmaxf((v3 - mean) * rs * gv.w + bv.w, 0.f));
    *(ushort4*)(xr + (size_t)node * 256 + lane * 4) = *(const ushort4*)tb;
}

// ---------------- pooling stage 1: partial conf-weighted sums over 64-node chunks ----------------
__global__ __launch_bounds__(256) void pool1_k(
    const bf16* __restrict__ xr, const float* __restrict__ conf, float* __restrict__ partial)
{
    const int b = blockIdx.x, chunk = blockIdx.y, c = threadIdx.x;
    float acc = 0.0f;
    for (int n = 0; n < 64; ++n) {
        const int node = b * 1024 + chunk * 64 + n;
        acc += conf[node] * b2f(xr[(size_t)node * 256 + c]);
    }
    partial[(size_t)(b * 16 + chunk) * 256 + c] = acc;
}

// ---------------- pooling stage 2 + head ----------------
__global__ __launch_bounds__(256) void pool2_k(
    const float* __restrict__ partial, const float* __restrict__ conf,
    const float* __restrict__ Wh, const float* __restrict__ bh, float* __restrict__ out)
{
    const int b = blockIdx.x, tid = threadIdx.x;
    __shared__ float red[256];
    __shared__ float pooled[256];
    float pc = 0.0f;
    for (int ch = 0; ch < 16; ++ch) pc += partial[(size_t)(b * 16 + ch) * 256 + tid];
    float s = conf[b * 1024 + tid] + conf[b * 1024 + 256 + tid]
            + conf[b * 1024 + 512 + tid] + conf[b * 1024 + 768 + tid];
    red[tid] = s; __syncthreads();
    for (int st = 128; st > 0; st >>= 1) { if (tid < st) red[tid] += red[tid + st]; __syncthreads(); }
    const float denom = fmaxf(red[0], 1e-8f);
    pooled[tid] = pc / denom;
    __syncthreads();
    if (tid < NS_) {
        float o = bh[tid];
        for (int c = 0; c < 256; ++c) o += pooled[c] * Wh[c * NS_ + tid];
        out[b * NS_ + tid] = o;
    }
}

extern "C" void kernel_launch(void* const* d_in, const int* in_sizes, int n_in,
                              void* d_out, int out_size, void* d_ws, size_t ws_size,
                              hipStream_t stream) {
    const float* x    = (const float*)d_in[0];
    const int*   ei   = (const int*)d_in[1];
    const int*   et   = (const int*)d_in[2];
    const float* Wq   = (const float*)d_in[3];  const float* bq  = (const float*)d_in[4];
    const float* Wk   = (const float*)d_in[5];  const float* bk  = (const float*)d_in[6];
    const float* Wv   = (const float*)d_in[7];  const float* bv  = (const float*)d_in[8];
    const float* Wg   = (const float*)d_in[9];  const float* bg  = (const float*)d_in[10];
    const float* lag  = (const float*)d_in[11]; const float* lab = (const float*)d_in[12];
    const float* Wc1  = (const float*)d_in[13]; const float* bc1 = (const float*)d_in[14];
    const float* Wc2  = (const float*)d_in[15]; const float* bc2 = (const float*)d_in[16];
    const float* Wm   = (const float*)d_in[17]; const float* bm  = (const float*)d_in[18];
    const float* l1g  = (const float*)d_in[19]; const float* l1b = (const float*)d_in[20];
    const float* Wrel = (const float*)d_in[21]; const float* Wroot = (const float*)d_in[22];
    const float* brg  = (const float*)d_in[23];
    const float* l2g  = (const float*)d_in[24]; const float* l2b = (const float*)d_in[25];
    const float* Wh   = (const float*)d_in[26]; const float* bh  = (const float*)d_in[27];
    const int* esrc = ei;
    const int* edst = ei + E_;

    char* w8 = (char*)d_ws;
    bf16*  xb    = (bf16*)(w8 + 0);            // 8 MB
    bf16*  qb    = (bf16*)(w8 + 8388608);      // 8 MB
    bf16*  kb    = (bf16*)(w8 + 16777216);     // 8 MB
    bf16*  vb    = (bf16*)(w8 + 25165824);     // 8 MB
    bf16*  vtb   = (bf16*)(w8 + 33554432);     // 8 MB
    bf16*  sP    = (bf16*)(w8 + 41943040);     // 32 MB  scores -> P in place
    bf16*  hbuf  = (bf16*)(w8 + 41943040);     // 64 MB  [BN,2048] (reuses sP/cat1/cat2 after attn phase)
    bf16*  cat1  = (bf16*)(w8 + 75497472);     // 16 MB  [aout | xb]
    bf16*  cat2  = (bf16*)(w8 + 92274688);     // 16 MB  [xb | weighted]
    bf16*  gate  = (bf16*)(w8 + 109051904);    // 8 MB
    bf16*  valid = (bf16*)(w8 + 117440512);    // 8 MB
    bf16*  t1    = (bf16*)(w8 + 125829120);    // 4 MB
    bf16*  xm    = (bf16*)(w8 + 130023424);    // 8 MB
    bf16*  xn    = (bf16*)(w8 + 138412032);    // 8 MB
    float* agg   = (float*)(w8 + 155189248);   // 16 MB fp32 root projection
    bf16*  xr    = (bf16*)(w8 + 171966464);    // 8 MB
    float* conf  = (float*)(w8 + 180355072);   // 64 KB
    float* part  = (float*)(w8 + 180944896);   // 256 KB
    bf16*  WT    = (bf16*)(w8 + 181207040);    // ~2.2 MB transposed weights
    bf16* WqT   = WT;
    bf16* WkT   = WT + 65536;
    bf16* WvT   = WT + 131072;
    bf16* WrootT= WT + 196608;
    bf16* WgT   = WT + 262144;     // [256,512]
    bf16* WmT   = WT + 393216;     // [256,512]
    bf16* Wc1T  = WT + 524288;     // [128,256]
    bf16* WrelT = WT + 557056;     // 8 x [256,256] == [2048,256]
    int*  deg    = (int*)(w8 + 183500800);     // 64 KB
    int*  cnt8i  = (int*)(w8 + 183566336);     // 512 KB
    int*  rowptr = (int*)(w8 + 184090624);     // 64 KB + 4
    int*  cursor = (int*)(w8 + 184157184);     // 64 KB
    int*  elist  = (int*)(w8 + 184222720);     // 1 MB
    float* outp = (float*)d_out;

    dim3 blk(256);

    // --- prep: convert/transpose ---
    cvt_x_k<<<BNC_ / 256, blk, 0, stream>>>(x, xb, cat1, cat2);
    transpose_k<float><<<dim3(8, 8, 1),  blk, 0, stream>>>(Wq,   WqT,    256, 256, 0, 0);
    transpose_k<float><<<dim3(8, 8, 1),  blk, 0, stream>>>(Wk,   WkT,    256, 256, 0, 0);
    transpose_k<float><<<dim3(8, 8, 1),  blk, 0, stream>>>(Wv,   WvT,    256, 256, 0, 0);
    transpose_k<float><<<dim3(8, 8, 1),  blk, 0, stream>>>(Wroot,WrootT, 256, 256, 0, 0);
    transpose_k<float><<<dim3(8, 16, 1), blk, 0, stream>>>(Wg,   WgT,    512, 256, 0, 0);
    transpose_k<float><<<dim3(8, 16, 1), blk, 0, stream>>>(Wm,   WmT,    512, 256, 0, 0);
    transpose_k<float><<<dim3(4, 8, 1),  blk, 0, stream>>>(Wc1,  Wc1T,   256, 128, 0, 0);
    transpose_k<float><<<dim3(8, 8, 8),  blk, 0, stream>>>(Wrel, WrelT,  256, 256, 65536, 65536);

    // --- CSR build (independent of dense path) ---
    hipMemsetAsync(deg, 0, BN_ * sizeof(int), stream);
    hipMemsetAsync(cnt8i, 0, (size_t)BN_ * R_ * sizeof(int), stream);
    count2_k<<<E_ / 256, blk, 0, stream>>>(edst, et, deg, cnt8i);
    scan_k<<<1, blk, 0, stream>>>(deg, rowptr, cursor);
    fill_k<<<E_ / 256, blk, 0, stream>>>(esrc, edst, et, cursor, elist);

    // --- QKV projections (bf16 MFMA) ---
    gemm_bf16<0, bf16><<<dim3(2, 128, 1), blk, 0, stream>>>(xb, 256, 0, WqT, 256, 0, qb, 256, 0, bq, 256);
    gemm_bf16<0, bf16><<<dim3(2, 128, 1), blk, 0, stream>>>(xb, 256, 0, WkT, 256, 0, kb, 256, 0, bk, 256);
    gemm_bf16<0, bf16><<<dim3(2, 128, 1), blk, 0, stream>>>(xb, 256, 0, WvT, 256, 0, vb, 256, 0, bv, 256);
    // V^T per batch for the PV GEMM B-operand
    transpose_k<bf16><<<dim3(8, 32, 16), blk, 0, stream>>>(vb, vtb, 1024, 256, 262144, 262144);

    // --- attention: scores = Q @ K^T (batched), softmax, O = P @ V ---
    gemm_bf16<0, bf16><<<dim3(8, 8, 16), blk, 0, stream>>>(
        qb, 256, 262144, kb, 256, 262144, sP, 1024, 1048576, nullptr, 256);
    softmax_k<<<BN_, blk, 0, stream>>>(sP);
    gemm_bf16<0, bf16><<<dim3(2, 8, 16), blk, 0, stream>>>(
        sP, 1024, 1048576, vtb, 1024, 262144, cat1, 512, 524288, nullptr, 1024);

    // --- gate = sigmoid([aout|x] @ Wg + bg), blended LN ---
    gemm_bf16<2, bf16><<<dim3(2, 128, 1), blk, 0, stream>>>(cat1, 512, 0, WgT, 512, 0, gate, 256, 0, bg, 512);
    blend_ln_k<<<BN_, blk, 0, stream>>>(gate, cat1, x, valid, lag, lab);

    // --- confidence ---
    gemm_bf16<1, bf16><<<dim3(1, 128, 1), blk, 0, stream>>>(valid, 256, 0, Wc1T, 256, 0, t1, 128, 0, bc1, 256);
    conf_k<<<BN_ / 4, blk, 0, stream>>>(t1, Wc2, bc2, conf);
    weighted_k<<<BNC_ / 256, blk, 0, stream>>>(valid, conf, cat2);

    // --- mixer + LN1 ---
    gemm_bf16<1, bf16><<<dim3(2, 128, 1), blk, 0, stream>>>(cat2, 512, 0, WmT, 512, 0, xm, 256, 0, bm, 512);
    ln_k<bf16, 0><<<BN_, blk, 0, stream>>>(xm, xn, l1g, l1b);

    // --- RGCN: root GEMM (fp32 out), one fused 8-relation GEMM, gather+LN ---
    gemm_bf16<0, float><<<dim3(2, 128, 1), blk, 0, stream>>>(xn, 256, 0, WrootT, 256, 0, agg, 256, 0, brg, 256);
    gemm_bf16<0, bf16><<<dim3(16, 128, 1), blk, 0, stream>>>(
        xn, 256, 0, WrelT, 256, 0, hbuf, 2048, 0, nullptr, 256);
    gather_ln_k<<<BN_ / 4, blk, 0, stream>>>(rowptr, elist, hbuf, cnt8i, agg, l2g, l2b, xr);

    // --- pool + head ---
    pool1_k<<<dim3(B_, 16), blk, 0, stream>>>(xr, conf, part);
    pool2_k<<<B_, blk, 0, stream>>>(part, conf, Wh, bh, outp);
}

// Round 4
// 307.843 us; speedup vs baseline: 22.0126x; 1.2893x over previous
//
#include <hip/hip_runtime.h>
#include <hip/hip_bf16.h>

#define B_ 16
#define N_ 1024
#define C_ 256
#define R_ 8
#define E_ 262144
#define NS_ 32
#define BN_ (B_*N_)
#define BNC_ (BN_*C_)

typedef __hip_bfloat16 bf16;
typedef __attribute__((ext_vector_type(4))) float f32x4;
typedef __attribute__((ext_vector_type(8))) short bf16x8;

__device__ __forceinline__ float b2f(bf16 x) { return __bfloat162float(x); }
__device__ __forceinline__ bf16  f2b(float x) { return __float2bfloat16(x); }
__device__ __forceinline__ float us2f(unsigned short u) { return __uint_as_float((unsigned)u << 16); }

// async global->LDS, 16B per lane (wave-uniform LDS base + lane*16 implicit)
__device__ __forceinline__ void gload16(const void* g, void* l) {
    auto gp = (const __attribute__((address_space(1))) void*)(unsigned long long)g;
    auto lp = (__attribute__((address_space(3))) void*)(unsigned)(unsigned long long)l;
    __builtin_amdgcn_global_load_lds(gp, lp, 16, 0, 0);
}

// ---------------- bf16 MFMA GEMM: C = act(A[M,K] @ B^T + bias) ----------------
// A row-major [M,K] (lda), B stored [N,K] row-major (ldb), C bf16 [M,N] (ldc).
// 128x128 tile, BK=32, 4 waves (2x2 of 64x64), mfma_f32_16x16x32_bf16.
// Epilogue bounces through LDS for coalesced 16B stores.
// bias covers cols 0-255, bias2 256-511, bias3 512-767 (for fused QKV).
template<int ACT>
__global__ __launch_bounds__(256) void gemm_bf16(
    const bf16* __restrict__ A, int lda, long long sA,
    const bf16* __restrict__ Bm, int ldb, long long sB,
    bf16* __restrict__ Cc, int ldc, long long sC,
    const float* __restrict__ bias, const float* __restrict__ bias2,
    const float* __restrict__ bias3, int K)
{
    __shared__ short sbuf[17408];        // As[4096] + Bs[4096]; reused as Cs[128*136]
    short* As = sbuf;
    short* Bs = sbuf + 4096;
    const int tid = threadIdx.x;
    const int lane = tid & 63, w = tid >> 6;
    const int wr = w >> 1, wc = w & 1;
    const int bm = blockIdx.y * 128, bn = blockIdx.x * 128;
    const bf16* Ab = A + (size_t)blockIdx.z * sA;
    const bf16* Bb = Bm + (size_t)blockIdx.z * sB;
    bf16* Cb = Cc + (size_t)blockIdx.z * sC;

    const int rg = lane >> 2;            // staging row within 16-row group
    const int kg = (lane & 3) * 8;       // staging k offset (elements)

    f32x4 acc[4][4];
    const f32x4 zz = {0.f, 0.f, 0.f, 0.f};
    #pragma unroll
    for (int i = 0; i < 4; ++i)
        #pragma unroll
        for (int j = 0; j < 4; ++j) acc[i][j] = zz;

    for (int k0 = 0; k0 < K; k0 += 32) {
        __syncthreads();
        #pragma unroll
        for (int t = 0; t < 2; ++t) {
            gload16(Ab + (size_t)(bm + t*64 + w*16 + rg) * lda + k0 + kg, As + t*2048 + w*512);
            gload16(Bb + (size_t)(bn + t*64 + w*16 + rg) * ldb + k0 + kg, Bs + t*2048 + w*512);
        }
        __syncthreads();
        bf16x8 af[4], bfr[4];
        #pragma unroll
        for (int i = 0; i < 4; ++i)
            af[i] = *(const bf16x8*)&As[(wr*64 + i*16 + (lane & 15))*32 + (lane >> 4)*8];
        #pragma unroll
        for (int j = 0; j < 4; ++j)
            bfr[j] = *(const bf16x8*)&Bs[(wc*64 + j*16 + (lane & 15))*32 + (lane >> 4)*8];
        #pragma unroll
        for (int i = 0; i < 4; ++i)
            #pragma unroll
            for (int j = 0; j < 4; ++j)
                acc[i][j] = __builtin_amdgcn_mfma_f32_16x16x32_bf16(af[i], bfr[j], acc[i][j], 0, 0, 0);
    }

    // epilogue: acc -> LDS (bf16, padded stride 136) -> coalesced 16B global stores
    __syncthreads();
    const int er = (lane >> 4) * 4, ec = lane & 15;
    #pragma unroll
    for (int j = 0; j < 4; ++j) {
        const int col = bn + wc*64 + j*16 + ec;
        float bvv = 0.0f;
        if (bias) {
            const int seg = col >> 8;
            const float* bp = (seg == 0) ? bias : (seg == 1 ? bias2 : bias3);
            bvv = bp[col & 255];
        }
        #pragma unroll
        for (int i = 0; i < 4; ++i) {
            #pragma unroll
            for (int p = 0; p < 4; ++p) {
                float val = acc[i][j][p] + bvv;
                if (ACT == 1) val = fmaxf(val, 0.0f);
                if (ACT == 2) val = 1.0f / (1.0f + __expf(-val));
                *(bf16*)&sbuf[(wr*64 + i*16 + er + p)*136 + wc*64 + j*16 + ec] = f2b(val);
            }
        }
    }
    __syncthreads();
    #pragma unroll
    for (int it = 0; it < 8; ++it) {
        const int ch = tid + it*256;               // 2048 chunks of 8 elements
        const int row = ch >> 4, cp = (ch & 15) * 8;
        bf16x8 vv = *(const bf16x8*)&sbuf[row*136 + cp];
        *(bf16x8*)&Cb[(size_t)(bm + row) * ldc + bn + cp] = vv;
    }
}

// ---------------- all weight transposes fp32[K,Nn] -> bf16[Nn,K], one dispatch ----------------
// WT element offsets: WqkvT@0 [768,256]; WgT@196608 [256,512]; WmT@327680 [256,512];
// Wc1T@458752 [128,256]; WBIG@491520 [2304,256] = 8x WrelT then WrootT.
__global__ __launch_bounds__(256) void prep_w_k(
    const float* __restrict__ Wq, const float* __restrict__ Wk, const float* __restrict__ Wv,
    const float* __restrict__ Wg, const float* __restrict__ Wm, const float* __restrict__ Wc1,
    const float* __restrict__ Wrel, const float* __restrict__ Wroot, bf16* __restrict__ WT)
{
    int t = blockIdx.x;
    const float* in; bf16* out; int K, Nn;
    if (t < 192)      { int wsel = t >> 6; t &= 63;
                        in = wsel == 0 ? Wq : (wsel == 1 ? Wk : Wv);
                        out = WT + wsel*65536; K = 256; Nn = 256; }
    else if (t < 320) { t -= 192; in = Wg;  out = WT + 196608; K = 512; Nn = 256; }
    else if (t < 448) { t -= 320; in = Wm;  out = WT + 327680; K = 512; Nn = 256; }
    else if (t < 480) { t -= 448; in = Wc1; out = WT + 458752; K = 256; Nn = 128; }
    else if (t < 992) { t -= 480; int r = t >> 6; t &= 63;
                        in = Wrel + (size_t)r*65536; out = WT + 491520 + r*65536; K = 256; Nn = 256; }
    else              { t -= 992; in = Wroot; out = WT + 491520 + 524288; K = 256; Nn = 256; }
    const int tpr = Nn >> 5;
    const int n0 = (t % tpr) * 32, k0 = (t / tpr) * 32;
    __shared__ float tile[32][33];
    const int tx = threadIdx.x & 31, ty = threadIdx.x >> 5;
    #pragma unroll
    for (int i = 0; i < 4; ++i) {
        int r = ty + i*8;
        tile[r][tx] = in[(size_t)(k0 + r) * Nn + n0 + tx];
    }
    __syncthreads();
    #pragma unroll
    for (int i = 0; i < 4; ++i) {
        int r = ty + i*8;
        out[(size_t)(n0 + r) * K + k0 + tx] = f2b(tile[tx][r]);
    }
}

// ---------------- V^T: qkv V-part [1024,256] (ld 768) -> vtb [256,1024] per batch ----------------
__global__ __launch_bounds__(256) void vtrans_k(
    const bf16* __restrict__ in, bf16* __restrict__ out)
{
    __shared__ float tile[32][33];
    in  += (size_t)blockIdx.z * 786432 + 512;     // V columns of qkv
    out += (size_t)blockIdx.z * 262144;
    const int n0 = blockIdx.x * 32, k0 = blockIdx.y * 32;
    const int tx = threadIdx.x & 31, ty = threadIdx.x >> 5;
    #pragma unroll
    for (int i = 0; i < 4; ++i) {
        int r = ty + i*8;
        tile[r][tx] = b2f(in[(size_t)(k0 + r) * 768 + n0 + tx]);
    }
    __syncthreads();
    #pragma unroll
    for (int i = 0; i < 4; ++i) {
        int r = ty + i*8;
        out[(size_t)(n0 + r) * 1024 + k0 + tx] = f2b(tile[tx][r]);
    }
}

// ---------------- x fp32 -> bf16 (xb, cat1 right half, cat2 left half), 4 el/thread ----------------
__global__ __launch_bounds__(256) void cvt_x_k(const float* __restrict__ x,
    bf16* __restrict__ xb, bf16* __restrict__ cat1, bf16* __restrict__ cat2)
{
    const int i4 = (blockIdx.x * 256 + threadIdx.x) * 4;
    const float4 xv = *(const float4*)(x + i4);
    bf16 bv[4] = { f2b(xv.x), f2b(xv.y), f2b(xv.z), f2b(xv.w) };
    const ushort4 pack = *(const ushort4*)bv;
    const int row = i4 >> 8, col = i4 & 255;
    *(ushort4*)(xb + i4) = pack;
    *(ushort4*)(cat1 + (size_t)row * 512 + 256 + col) = pack;
    *(ushort4*)(cat2 + (size_t)row * 512 + col) = pack;
}

// ---------------- row softmax over 1024 bf16 scores in place (pre-scale 1/16) ----------------
__global__ __launch_bounds__(256) void softmax_k(bf16* __restrict__ s)
{
    const int row = blockIdx.x, tid = threadIdx.x;
    const int lane = tid & 63, wid = tid >> 6;
    bf16* rp = s + (size_t)row * 1024 + tid * 4;
    __shared__ float red[8];
    const ushort4 sv = *(const ushort4*)rp;
    float v0 = us2f(sv.x) * 0.0625f, v1 = us2f(sv.y) * 0.0625f;
    float v2 = us2f(sv.z) * 0.0625f, v3 = us2f(sv.w) * 0.0625f;
    float m = fmaxf(fmaxf(v0, v1), fmaxf(v2, v3));
    #pragma unroll
    for (int o = 32; o >= 1; o >>= 1) m = fmaxf(m, __shfl_xor(m, o));
    if (lane == 0) red[wid] = m;
    __syncthreads();
    const float mx = fmaxf(fmaxf(red[0], red[1]), fmaxf(red[2], red[3]));
    float e0 = __expf(v0 - mx), e1 = __expf(v1 - mx), e2 = __expf(v2 - mx), e3 = __expf(v3 - mx);
    float sm = e0 + e1 + e2 + e3;
    #pragma unroll
    for (int o = 32; o >= 1; o >>= 1) sm += __shfl_xor(sm, o);
    if (lane == 0) red[4 + wid] = sm;
    __syncthreads();
    const float inv = 1.0f / (red[4] + red[5] + red[6] + red[7]);
    bf16 ov[4] = { f2b(e0 * inv), f2b(e1 * inv), f2b(e2 * inv), f2b(e3 * inv) };
    *(ushort4*)rp = *(const ushort4*)ov;
}

// ---------------- LN over C=256 (wave per row, 4 ch/lane), bf16 in/out ----------------
template<int RELU>
__global__ __launch_bounds__(256) void ln_k(
    const bf16* __restrict__ in, bf16* __restrict__ out,
    const float* __restrict__ g, const float* __restrict__ bta)
{
    const int node = blockIdx.x * 4 + (threadIdx.x >> 6);
    const int lane = threadIdx.x & 63;
    const ushort4 iv = *(const ushort4*)(in + (size_t)node * 256 + lane * 4);
    float v0 = us2f(iv.x), v1 = us2f(iv.y), v2 = us2f(iv.z), v3 = us2f(iv.w);
    float s  = v0 + v1 + v2 + v3;
    float sq = v0*v0 + v1*v1 + v2*v2 + v3*v3;
    #pragma unroll
    for (int o = 32; o >= 1; o >>= 1) { s += __shfl_xor(s, o); sq += __shfl_xor(sq, o); }
    const float mean = s * (1.0f / 256.0f);
    const float var  = sq * (1.0f / 256.0f) - mean * mean;
    const float rs = rsqrtf(var + 1e-5f);
    const float4 gv = *(const float4*)(g + lane * 4);
    const float4 bv = *(const float4*)(bta + lane * 4);
    float y0 = (v0 - mean) * rs * gv.x + bv.x;
    float y1 = (v1 - mean) * rs * gv.y + bv.y;
    float y2 = (v2 - mean) * rs * gv.z + bv.z;
    float y3 = (v3 - mean) * rs * gv.w + bv.w;
    if (RELU) { y0 = fmaxf(y0, 0.f); y1 = fmaxf(y1, 0.f); y2 = fmaxf(y2, 0.f); y3 = fmaxf(y3, 0.f); }
    bf16 ov[4] = { f2b(y0), f2b(y1), f2b(y2), f2b(y3) };
    *(ushort4*)(out + (size_t)node * 256 + lane * 4) = *(const ushort4*)ov;
}

// ---------------- gated blend + LN (wave per row) ----------------
__global__ __launch_bounds__(256) void blend_ln_k(
    const bf16* __restrict__ gate, const bf16* __restrict__ cat1,
    const float* __restrict__ x, bf16* __restrict__ valid,
    const float* __restrict__ g, const float* __restrict__ bta)
{
    const int node = blockIdx.x * 4 + (threadIdx.x >> 6);
    const int lane = threadIdx.x & 63;
    const ushort4 gt4 = *(const ushort4*)(gate + (size_t)node * 256 + lane * 4);
    const ushort4 ao4 = *(const ushort4*)(cat1 + (size_t)node * 512 + lane * 4);
    const float4  xv4 = *(const float4*)(x + (size_t)node * 256 + lane * 4);
    float g0 = us2f(gt4.x), g1 = us2f(gt4.y), g2 = us2f(gt4.z), g3 = us2f(gt4.w);
    float v0 = g0 * us2f(ao4.x) + (1.f - g0) * xv4.x;
    float v1 = g1 * us2f(ao4.y) + (1.f - g1) * xv4.y;
    float v2 = g2 * us2f(ao4.z) + (1.f - g2) * xv4.z;
    float v3 = g3 * us2f(ao4.w) + (1.f - g3) * xv4.w;
    float s  = v0 + v1 + v2 + v3;
    float sq = v0*v0 + v1*v1 + v2*v2 + v3*v3;
    #pragma unroll
    for (int o = 32; o >= 1; o >>= 1) { s += __shfl_xor(s, o); sq += __shfl_xor(sq, o); }
    const float mean = s * (1.0f / 256.0f);
    const float var  = sq * (1.0f / 256.0f) - mean * mean;
    const float rs = rsqrtf(var + 1e-5f);
    const float4 gv = *(const float4*)(g + lane * 4);
    const float4 bv = *(const float4*)(bta + lane * 4);
    bf16 ov[4] = { f2b((v0 - mean) * rs * gv.x + bv.x), f2b((v1 - mean) * rs * gv.y + bv.y),
                   f2b((v2 - mean) * rs * gv.z + bv.z), f2b((v3 - mean) * rs * gv.w + bv.w) };
    *(ushort4*)(valid + (size_t)node * 256 + lane * 4) = *(const ushort4*)ov;
}

// ---------------- confidence layer2 + weighted (wave per node) ----------------
__global__ __launch_bounds__(256) void conf_w_k(
    const bf16* __restrict__ t1, const float* __restrict__ Wc2, const float* __restrict__ bc2,
    const bf16* __restrict__ valid, float* __restrict__ conf, bf16* __restrict__ cat2)
{
    const int node = blockIdx.x * 4 + (threadIdx.x >> 6);
    const int lane = threadIdx.x & 63;
    float a = b2f(t1[(size_t)node * 128 + lane]) * Wc2[lane]
            + b2f(t1[(size_t)node * 128 + 64 + lane]) * Wc2[64 + lane];
    #pragma unroll
    for (int o = 32; o >= 1; o >>= 1) a += __shfl_xor(a, o);
    const float c = 1.0f / (1.0f + __expf(-(a + bc2[0])));
    if (lane == 0) conf[node] = c;
    const ushort4 vv = *(const ushort4*)(valid + (size_t)node * 256 + lane * 4);
    bf16 ov[4] = { f2b(us2f(vv.x) * c), f2b(us2f(vv.y) * c), f2b(us2f(vv.z) * c), f2b(us2f(vv.w) * c) };
    *(ushort4*)(cat2 + (size_t)node * 512 + 256 + lane * 4) = *(const ushort4*)ov;
}

// ---------------- CSR build ----------------
__global__ __launch_bounds__(256) void count2_k(
    const int* __restrict__ dst, const int* __restrict__ et,
    int* __restrict__ deg, int* __restrict__ cnt8)
{
    const int e = blockIdx.x * 256 + threadIdx.x;
    if (e < E_) {
        const int d = dst[e];
        atomicAdd(&deg[d], 1);
        atomicAdd(&cnt8[d * 8 + et[e]], 1);
    }
}

__global__ __launch_bounds__(256) void scan_k(
    const int* __restrict__ deg, int* __restrict__ rowptr, int* __restrict__ cursor)
{
    __shared__ int part[256];
    const int tid = threadIdx.x;
    const int base = tid * 64;
    int s = 0;
    for (int i = 0; i < 64; ++i) s += deg[base + i];
    part[tid] = s; __syncthreads();
    for (int off = 1; off < 256; off <<= 1) {
        int t = (tid >= off) ? part[tid - off] : 0;
        __syncthreads();
        part[tid] += t;
        __syncthreads();
    }
    int run = (tid == 0) ? 0 : part[tid - 1];
    for (int i = 0; i < 64; ++i) {
        rowptr[base + i] = run;
        cursor[base + i] = run;
        run += deg[base + i];
    }
    if (tid == 255) rowptr[BN_] = run;
}

__global__ __launch_bounds__(256) void fill_k(
    const int* __restrict__ src, const int* __restrict__ dst, const int* __restrict__ et,
    int* __restrict__ cursor, int* __restrict__ elist)
{
    const int e = blockIdx.x * 256 + threadIdx.x;
    if (e < E_) {
        const int pos = atomicAdd(&cursor[dst[e]], 1);
        elist[pos] = src[e] | (et[e] << 16);
    }
}

// ---------------- RGCN gather + root + bias + LN2 + relu (wave per node) ----------------
// h: [BN, 2304] = [8 x rel-transformed (2048) | root-transformed (256)] bf16
__global__ __launch_bounds__(256) void gather_ln_k(
    const int* __restrict__ rowptr, const int* __restrict__ elist,
    const bf16* __restrict__ h, const int* __restrict__ cnt8,
    const float* __restrict__ brg,
    const float* __restrict__ g, const float* __restrict__ bta,
    bf16* __restrict__ xr)
{
    const int node = blockIdx.x * 4 + (threadIdx.x >> 6);
    const int lane = threadIdx.x & 63;
    const int e0 = rowptr[node], e1 = rowptr[node + 1];
    float invc[8];
    #pragma unroll
    for (int r = 0; r < 8; ++r)
        invc[r] = 1.0f / fmaxf((float)cnt8[node * 8 + r], 1.0f);
    float a0 = 0.f, a1 = 0.f, a2 = 0.f, a3 = 0.f;
    for (int e = e0; e < e1; ++e) {
        const int pe = elist[e];
        const int srcn = pe & 0xffff, rel = pe >> 16;
        const float wgt = invc[rel];
        const ushort4 hv = *(const ushort4*)(h + (size_t)srcn * 2304 + rel * 256 + lane * 4);
        a0 += wgt * us2f(hv.x); a1 += wgt * us2f(hv.y);
        a2 += wgt * us2f(hv.z); a3 += wgt * us2f(hv.w);
    }
    const ushort4 rv = *(const ushort4*)(h + (size_t)node * 2304 + 2048 + lane * 4);
    const float4 bg4 = *(const float4*)(brg + lane * 4);
    const float v0 = a0 + us2f(rv.x) + bg4.x, v1 = a1 + us2f(rv.y) + bg4.y;
    const float v2 = a2 + us2f(rv.z) + bg4.z, v3 = a3 + us2f(rv.w) + bg4.w;
    float s  = v0 + v1 + v2 + v3;
    float sq = v0*v0 + v1*v1 + v2*v2 + v3*v3;
    #pragma unroll
    for (int m = 32; m >= 1; m >>= 1) { s += __shfl_xor(s, m); sq += __shfl_xor(sq, m); }
    const float mean = s * (1.0f / 256.0f);
    const float var  = sq * (1.0f / 256.0f) - mean * mean;
    const float rs = rsqrtf(var + 1e-5f);
    const float4 gv = *(const float4*)(g + lane * 4);
    const float4 bv = *(const float4*)(bta + lane * 4);
    bf16 tb[4] = { f2b(fmaxf((v0 - mean) * rs * gv.x + bv.x, 0.f)),
                   f2b(fmaxf((v1 - mean) * rs * gv.y + bv.y, 0.f)),
                   f2b(fmaxf((v2 - mean) * rs * gv.z + bv.z, 0.f)),
                   f2b(fmaxf((v3 - mean) * rs * gv.w + bv.w, 0.f)) };
    *(ushort4*)(xr + (size_t)node * 256 + lane * 4) = *(const ushort4*)tb;
}

// ---------------- pooling stage 1 ----------------
__global__ __launch_bounds__(256) void pool1_k(
    const bf16* __restrict__ xr, const float* __restrict__ conf, float* __restrict__ partial)
{
    const int b = blockIdx.x, chunk = blockIdx.y, c = threadIdx.x;
    float acc = 0.0f;
    for (int n = 0; n < 64; ++n) {
        const int node = b * 1024 + chunk * 64 + n;
        acc += conf[node] * b2f(xr[(size_t)node * 256 + c]);
    }
    partial[(size_t)(b * 16 + chunk) * 256 + c] = acc;
}

// ---------------- pooling stage 2 + head ----------------
__global__ __launch_bounds__(256) void pool2_k(
    const float* __restrict__ partial, const float* __restrict__ conf,
    const float* __restrict__ Wh, const float* __restrict__ bh, float* __restrict__ out)
{
    const int b = blockIdx.x, tid = threadIdx.x;
    __shared__ float red[256];
    __shared__ float pooled[256];
    float pc = 0.0f;
    for (int ch = 0; ch < 16; ++ch) pc += partial[(size_t)(b * 16 + ch) * 256 + tid];
    float s = conf[b * 1024 + tid] + conf[b * 1024 + 256 + tid]
            + conf[b * 1024 + 512 + tid] + conf[b * 1024 + 768 + tid];
    red[tid] = s; __syncthreads();
    for (int st = 128; st > 0; st >>= 1) { if (tid < st) red[tid] += red[tid + st]; __syncthreads(); }
    const float denom = fmaxf(red[0], 1e-8f);
    pooled[tid] = pc / denom;
    __syncthreads();
    if (tid < NS_) {
        float o = bh[tid];
        for (int c = 0; c < 256; ++c) o += pooled[c] * Wh[c * NS_ + tid];
        out[b * NS_ + tid] = o;
    }
}

extern "C" void kernel_launch(void* const* d_in, const int* in_sizes, int n_in,
                              void* d_out, int out_size, void* d_ws, size_t ws_size,
                              hipStream_t stream) {
    const float* x    = (const float*)d_in[0];
    const int*   ei   = (const int*)d_in[1];
    const int*   et   = (const int*)d_in[2];
    const float* Wq   = (const float*)d_in[3];  const float* bq  = (const float*)d_in[4];
    const float* Wk   = (const float*)d_in[5];  const float* bk  = (const float*)d_in[6];
    const float* Wv   = (const float*)d_in[7];  const float* bv  = (const float*)d_in[8];
    const float* Wg   = (const float*)d_in[9];  const float* bg  = (const float*)d_in[10];
    const float* lag  = (const float*)d_in[11]; const float* lab = (const float*)d_in[12];
    const float* Wc1  = (const float*)d_in[13]; const float* bc1 = (const float*)d_in[14];
    const float* Wc2  = (const float*)d_in[15]; const float* bc2 = (const float*)d_in[16];
    const float* Wm   = (const float*)d_in[17]; const float* bm  = (const float*)d_in[18];
    const float* l1g  = (const float*)d_in[19]; const float* l1b = (const float*)d_in[20];
    const float* Wrel = (const float*)d_in[21]; const float* Wroot = (const float*)d_in[22];
    const float* brg  = (const float*)d_in[23];
    const float* l2g  = (const float*)d_in[24]; const float* l2b = (const float*)d_in[25];
    const float* Wh   = (const float*)d_in[26]; const float* bh  = (const float*)d_in[27];
    const int* esrc = ei;
    const int* edst = ei + E_;

    char* w8 = (char*)d_ws;
    bf16*  qkv   = (bf16*)(w8 + 0);            // [16384,768]  25,165,824 B
    bf16*  hbuf  = (bf16*)(w8 + 0);            // [16384,2304] 75,497,472 B (reuses qkv/sP/cat1 region)
    bf16*  sP    = (bf16*)(w8 + 25165824);     // [16x1024x1024] 33,554,432 B
    bf16*  cat1  = (bf16*)(w8 + 58720256);     // [aout|xb] ld 512, 16,777,216 B
    bf16*  cat2  = (bf16*)(w8 + 75497472);     // [xb|weighted] ld 512, 16,777,216 B
    bf16*  gate  = (bf16*)(w8 + 92274688);     // 8 MB
    bf16*  valid = (bf16*)(w8 + 100663296);    // 8 MB
    bf16*  t1    = (bf16*)(w8 + 109051904);    // 4 MB
    bf16*  xm    = (bf16*)(w8 + 113246208);    // 8 MB
    bf16*  xb    = (bf16*)(w8 + 121634816);    // 8 MB
    bf16*  xn    = (bf16*)(w8 + 130023424);    // 8 MB
    bf16*  vtb   = (bf16*)(w8 + 138412032);    // 8 MB
    bf16*  xr    = (bf16*)(w8 + 146800640);    // 8 MB
    float* conf  = (float*)(w8 + 155189248);   // 64 KB
    float* part  = (float*)(w8 + 155254784);   // 256 KB
    bf16*  WT    = (bf16*)(w8 + 155516928);    // 2,162,688 B
    int*  deg    = (int*)(w8 + 157679616);     // 64 KB   (adjacent to cnt8i for one memset)
    int*  cnt8i  = (int*)(w8 + 157745152);     // 512 KB
    int*  rowptr = (int*)(w8 + 158269440);     // 64 KB + pad
    int*  cursor = (int*)(w8 + 158335232);     // 64 KB
    int*  elist  = (int*)(w8 + 158400768);     // 1 MB
    bf16* WqkvT = WT;                  // [768,256]
    bf16* WgT   = WT + 196608;         // [256,512]
    bf16* WmT   = WT + 327680;         // [256,512]
    bf16* Wc1T  = WT + 458752;         // [128,256]
    bf16* WBIG  = WT + 491520;         // [2304,256] = 8 x WrelT | WrootT
    float* outp = (float*)d_out;

    dim3 blk(256);

    // --- prep: weights (1 dispatch), x conversion, CSR build ---
    prep_w_k<<<1056, blk, 0, stream>>>(Wq, Wk, Wv, Wg, Wm, Wc1, Wrel, Wroot, WT);
    cvt_x_k<<<BNC_ / 1024, blk, 0, stream>>>(x, xb, cat1, cat2);
    hipMemsetAsync(deg, 0, 589824, stream);               // deg + cnt8i
    count2_k<<<E_ / 256, blk, 0, stream>>>(edst, et, deg, cnt8i);
    scan_k<<<1, blk, 0, stream>>>(deg, rowptr, cursor);
    fill_k<<<E_ / 256, blk, 0, stream>>>(esrc, edst, et, cursor, elist);

    // --- fused QKV projection: qkv[16384,768] ---
    gemm_bf16<0><<<dim3(6, 128, 1), blk, 0, stream>>>(
        xb, 256, 0, WqkvT, 256, 0, qkv, 768, 0, bq, bk, bv, 256);
    vtrans_k<<<dim3(8, 32, 16), blk, 0, stream>>>(qkv, vtb);

    // --- attention ---
    gemm_bf16<0><<<dim3(8, 8, 16), blk, 0, stream>>>(
        qkv, 768, 786432, qkv + 256, 768, 786432, sP, 1024, 1048576, nullptr, nullptr, nullptr, 256);
    softmax_k<<<BN_, blk, 0, stream>>>(sP);
    gemm_bf16<0><<<dim3(2, 8, 16), blk, 0, stream>>>(
        sP, 1024, 1048576, vtb, 1024, 262144, cat1, 512, 524288, nullptr, nullptr, nullptr, 1024);

    // --- gate, blend+LN ---
    gemm_bf16<2><<<dim3(2, 128, 1), blk, 0, stream>>>(
        cat1, 512, 0, WgT, 512, 0, gate, 256, 0, bg, nullptr, nullptr, 512);
    blend_ln_k<<<BN_ / 4, blk, 0, stream>>>(gate, cat1, x, valid, lag, lab);

    // --- confidence + weighted ---
    gemm_bf16<1><<<dim3(1, 128, 1), blk, 0, stream>>>(
        valid, 256, 0, Wc1T, 256, 0, t1, 128, 0, bc1, nullptr, nullptr, 256);
    conf_w_k<<<BN_ / 4, blk, 0, stream>>>(t1, Wc2, bc2, valid, conf, cat2);

    // --- mixer + LN1 ---
    gemm_bf16<1><<<dim3(2, 128, 1), blk, 0, stream>>>(
        cat2, 512, 0, WmT, 512, 0, xm, 256, 0, bm, nullptr, nullptr, 512);
    ln_k<0><<<BN_ / 4, blk, 0, stream>>>(xm, xn, l1g, l1b);

    // --- RGCN: one GEMM (8 relations + root), gather + LN2 ---
    gemm_bf16<0><<<dim3(18, 128, 1), blk, 0, stream>>>(
        xn, 256, 0, WBIG, 256, 0, hbuf, 2304, 0, nullptr, nullptr, nullptr, 256);
    gather_ln_k<<<BN_ / 4, blk, 0, stream>>>(rowptr, elist, hbuf, cnt8i, brg, l2g, l2b, xr);

    // --- pool + head ---
    pool1_k<<<dim3(B_, 16), blk, 0, stream>>>(xr, conf, part);
    pool2_k<<<B_, blk, 0, stream>>>(part, conf, Wh, bh, outp);
}